// Round 10
// baseline (78.864 us; speedup 1.0000x reference)
//
#include <hip/hip_runtime.h>

#define T_ 500
#define R_ 50
#define NS_ 1000
#define H1_ 32
#define H2_ 16
#define NEG_ 0.2f
#define NROWS_ (NS_ * R_)   // 50000

__device__ __forceinline__ float lrelu(float x) { return x >= 0.f ? x : NEG_ * x; }

// One block per t: y1[t][c] = sum_f x[t][f] * gc1_w[f][c],  x=[state(2)|payoff row(500)|noise(2)]
__global__ __launch_bounds__(256) void k1_xw(const float* __restrict__ state,
                                             const float* __restrict__ payoff,
                                             const float* __restrict__ noise,
                                             const float* __restrict__ w,
                                             float* __restrict__ y1) {
    __shared__ float xs[504];
    __shared__ float red[8][H1_];
    int t = blockIdx.x, tid = threadIdx.x;
    for (int u = tid; u < T_; u += 256) xs[2 + u] = payoff[t * T_ + u];
    if (tid == 0) {
        xs[0] = state[t * 2];     xs[1] = state[t * 2 + 1];
        xs[502] = noise[t * 2];   xs[503] = noise[t * 2 + 1];
    }
    __syncthreads();
    int c = tid & 31, kg = tid >> 5;   // 8 k-groups x 32 channels
    float acc = 0.f;
#pragma unroll 7
    for (int f = kg; f < 504; f += 8) acc += xs[f] * w[f * H1_ + c];
    red[kg][c] = acc;
    __syncthreads();
    if (tid < H1_) {
        float a = 0.f;
#pragma unroll
        for (int s = 0; s < 8; ++s) a += red[s][tid];
        y1[t * H1_ + tid] = a;
    }
}

// One block per t: h1row = lrelu(bn(adj[t]@y1 + b)); y2[t][c2] = h1row @ g2w
__global__ __launch_bounds__(256) void k2_adj_fused(const float* __restrict__ adj,
                                                    const float* __restrict__ y1,
                                                    const float* __restrict__ b,
                                                    const float* __restrict__ gamma,
                                                    const float* __restrict__ beta,
                                                    const float* __restrict__ w2,
                                                    float* __restrict__ y2) {
    __shared__ float arow[T_];
    __shared__ float red[8][H1_];
    __shared__ float h1row[H1_];
    int t = blockIdx.x, tid = threadIdx.x;
    for (int u = tid; u < T_; u += 256) arow[u] = adj[t * T_ + u];
    __syncthreads();
    int c = tid & 31, kg = tid >> 5;
    float acc = 0.f;
#pragma unroll 4
    for (int u = kg; u < T_; u += 8) acc += arow[u] * y1[u * H1_ + c];
    red[kg][c] = acc;
    __syncthreads();
    if (tid < H1_) {
        float a = 0.f;
#pragma unroll
        for (int s = 0; s < 8; ++s) a += red[s][tid];
        h1row[tid] = lrelu((a + b[tid]) * gamma[t] + beta[t]);
    }
    __syncthreads();
    if (tid < H2_) {
        float a = 0.f;
#pragma unroll
        for (int cc = 0; cc < H1_; ++cc) a += h1row[cc] * w2[cc * H2_ + tid];
        y2[t * H2_ + tid] = a;
    }
}

// One block per t: xfrow = lrelu(bn(adj[t]@y2 + b2)); part1[t][j] = xfrow @ aw[t*16..t*16+16)
__global__ __launch_bounds__(256) void k3_adj2_aw(const float* __restrict__ adj,
                                                  const float* __restrict__ y2,
                                                  const float* __restrict__ b2,
                                                  const float* __restrict__ gamma,
                                                  const float* __restrict__ beta,
                                                  const float* __restrict__ aw,
                                                  float* __restrict__ part1) {
    __shared__ float arow[T_];
    __shared__ float red[16][H2_];
    __shared__ float xfr[H2_];
    int t = blockIdx.x, tid = threadIdx.x;
    for (int u = tid; u < T_; u += 256) arow[u] = adj[t * T_ + u];
    __syncthreads();
    int c2 = tid & 15, kg = tid >> 4;  // 16 k-groups x 16 channels
    float acc = 0.f;
#pragma unroll 4
    for (int u = kg; u < T_; u += 16) acc += arow[u] * y2[u * H2_ + c2];
    red[kg][c2] = acc;
    __syncthreads();
    if (tid < H2_) {
        float a = 0.f;
#pragma unroll
        for (int s = 0; s < 16; ++s) a += red[s][tid];
        xfr[tid] = lrelu((a + b2[tid]) * gamma[t] + beta[t]);
    }
    __syncthreads();
    float acc0 = 0.f, acc1 = 0.f;
#pragma unroll
    for (int c = 0; c < H2_; ++c) {
        float xv = xfr[c];
        const float* awr = aw + (t * H2_ + c) * T_;
        acc0 += xv * awr[tid];
        if (tid < T_ - 256) acc1 += xv * awr[256 + tid];
    }
    part1[t * T_ + tid] = acc0;
    if (tid < T_ - 256) part1[t * T_ + 256 + tid] = acc1;
}

// Block (r, y=q*2+jb): partial logits over t-quarter q, j-half jb.
// part2[q][r*T+j] = sum_{t in q} dloc[r][t]*av[t][j] + part1[t][j]
__global__ __launch_bounds__(256) void k4_logits_part(const float* __restrict__ dloc,
                                                      const float* __restrict__ av,
                                                      const float* __restrict__ part1,
                                                      float* __restrict__ part2) {
    int r = blockIdx.x;
    int jb = blockIdx.y & 1, q = blockIdx.y >> 1;
    __shared__ float drow[125];
    int tid = threadIdx.x;
    int t0 = q * 125;
    if (tid < 125) drow[tid] = dloc[r * T_ + t0 + tid];
    __syncthreads();
    if (tid >= 250) return;
    int j = jb * 250 + tid;
    float acc = 0.f;
#pragma unroll 5
    for (int i = 0; i < 125; ++i) {
        int t = t0 + i;
        acc += drow[i] * av[t * T_ + j] + part1[t * T_ + j];
    }
    part2[q * (R_ * T_) + r * T_ + j] = acc;
}

// elog[x] = exp(sum_q part2[q][x])
__global__ __launch_bounds__(256) void k4_reduce_exp(const float* __restrict__ part2,
                                                     float* __restrict__ elog) {
    int gid = blockIdx.x * 256 + threadIdx.x;
    if (gid >= R_ * T_) return;
    float v = part2[gid] + part2[R_ * T_ + gid] +
              part2[2 * R_ * T_ + gid] + part2[3 * R_ * T_ + gid];
    elog[gid] = __expf(v);
}

// 4 rows per wave, straight-line: all 8 gu loads issued before any use (8KB
// MLP per wave), then each row {e-load, rcp(-log2), shuffle-reduce, store}.
// softmax identity: softmax(logit - log(-log u)) = elog * rcp(-log2 u) / rowsum.
__global__ __launch_bounds__(256) void k7_softmax(const float4* __restrict__ gu,
                                                  const float4* __restrict__ elog,
                                                  float4* __restrict__ out) {
    int wave = threadIdx.x >> 6;
    int lane = threadIdx.x & 63;
    int w = blockIdx.x * 4 + wave;   // wave id < 12500
    int row0 = w * 4;
    bool has1 = lane < 61;
    int i0 = lane, i1 = 64 + lane;

    const float4* g0p = gu + (size_t)row0 * 125;
    // issue all 8 gu loads back-to-back (independent, no loop-carried state)
    float4 a0 = g0p[i0];
    float4 a1 = has1 ? g0p[i1] : a0;
    float4 b0 = g0p[125 + i0];
    float4 b1 = has1 ? g0p[125 + i1] : b0;
    float4 c0 = g0p[250 + i0];
    float4 c1 = has1 ? g0p[250 + i1] : c0;
    float4 d0 = g0p[375 + i0];
    float4 d1 = has1 ? g0p[375 + i1] : d0;

#define ROWP(G0, G1, RR)                                                      \
    do {                                                                      \
        const float4* ep = elog + ((RR) % R_) * 125;                          \
        float4 e0 = ep[i0];                                                   \
        float4 e1 = has1 ? ep[i1] : e0;                                       \
        float p0 = e0.x * __builtin_amdgcn_rcpf(-__log2f(G0.x));              \
        float p1 = e0.y * __builtin_amdgcn_rcpf(-__log2f(G0.y));              \
        float p2 = e0.z * __builtin_amdgcn_rcpf(-__log2f(G0.z));              \
        float p3 = e0.w * __builtin_amdgcn_rcpf(-__log2f(G0.w));              \
        float p4 = 0.f, p5 = 0.f, p6 = 0.f, p7 = 0.f;                         \
        if (has1) {                                                           \
            p4 = e1.x * __builtin_amdgcn_rcpf(-__log2f(G1.x));                \
            p5 = e1.y * __builtin_amdgcn_rcpf(-__log2f(G1.y));                \
            p6 = e1.z * __builtin_amdgcn_rcpf(-__log2f(G1.z));                \
            p7 = e1.w * __builtin_amdgcn_rcpf(-__log2f(G1.w));                \
        }                                                                     \
        float s = ((p0 + p1) + (p2 + p3)) + ((p4 + p5) + (p6 + p7));          \
        _Pragma("unroll")                                                     \
        for (int off = 32; off > 0; off >>= 1) s += __shfl_xor(s, off);       \
        float inv = __builtin_amdgcn_rcpf(s);                                 \
        float4* op = out + (size_t)(RR) * 125;                                \
        float4 o0 = {p0 * inv, p1 * inv, p2 * inv, p3 * inv};                 \
        op[i0] = o0;                                                          \
        if (has1) {                                                           \
            float4 o1 = {p4 * inv, p5 * inv, p6 * inv, p7 * inv};             \
            op[i1] = o1;                                                      \
        }                                                                     \
    } while (0)

    ROWP(a0, a1, row0);
    ROWP(b0, b1, row0 + 1);
    ROWP(c0, c1, row0 + 2);
    ROWP(d0, d1, row0 + 3);
#undef ROWP
}

extern "C" void kernel_launch(void* const* d_in, const int* in_sizes, int n_in,
                              void* d_out, int out_size, void* d_ws, size_t ws_size,
                              hipStream_t stream) {
    const float* state  = (const float*)d_in[0];
    const float* dloc   = (const float*)d_in[1];
    const float* noise  = (const float*)d_in[2];
    const float* gu     = (const float*)d_in[3];
    const float* payoff = (const float*)d_in[4];
    const float* adj    = (const float*)d_in[5];
    const float* g1w    = (const float*)d_in[6];
    const float* g1b    = (const float*)d_in[7];
    const float* g2w    = (const float*)d_in[8];
    const float* g2b    = (const float*)d_in[9];
    const float* gamma  = (const float*)d_in[10];
    const float* beta   = (const float*)d_in[11];
    const float* aw     = (const float*)d_in[12];
    const float* av     = (const float*)d_in[13];
    float* out = (float*)d_out;

    float* ws     = (float*)d_ws;
    float* y1     = ws;           // 16000
    float* y2     = ws + 16000;   // 8000
    float* part1  = ws + 24000;   // 500*500 = 250000
    float* part2  = ws + 274000;  // 4*25000 = 100000
    float* elog   = ws + 374000;  // 25000   (total 399000 floats = 1.6 MB)

    k1_xw<<<T_, 256, 0, stream>>>(state, payoff, noise, g1w, y1);
    k2_adj_fused<<<T_, 256, 0, stream>>>(adj, y1, g1b, gamma, beta, g2w, y2);
    k3_adj2_aw<<<T_, 256, 0, stream>>>(adj, y2, g2b, gamma, beta, aw, part1);
    k4_logits_part<<<dim3(R_, 8), 256, 0, stream>>>(dloc, av, part1, part2);
    k4_reduce_exp<<<(R_ * T_ + 255) / 256, 256, 0, stream>>>(part2, elog);
    k7_softmax<<<NROWS_ / 16, 256, 0, stream>>>(
        (const float4*)gu, (const float4*)elog, (float4*)out);
}

// Round 11
// 73.457 us; speedup vs baseline: 1.0736x; 1.0736x over previous
//
#include <hip/hip_runtime.h>

#define T_ 500
#define R_ 50
#define NS_ 1000
#define H1_ 32
#define H2_ 16
#define NEG_ 0.2f
#define NROWS_ (NS_ * R_)   // 50000

__device__ __forceinline__ float lrelu(float x) { return x >= 0.f ? x : NEG_ * x; }

// One block per t: y1[t][c] = sum_f x[t][f] * gc1_w[f][c],  x=[state(2)|payoff row(500)|noise(2)]
__global__ __launch_bounds__(256) void k1_xw(const float* __restrict__ state,
                                             const float* __restrict__ payoff,
                                             const float* __restrict__ noise,
                                             const float* __restrict__ w,
                                             float* __restrict__ y1) {
    __shared__ float xs[504];
    __shared__ float red[8][H1_];
    int t = blockIdx.x, tid = threadIdx.x;
    for (int u = tid; u < T_; u += 256) xs[2 + u] = payoff[t * T_ + u];
    if (tid == 0) {
        xs[0] = state[t * 2];     xs[1] = state[t * 2 + 1];
        xs[502] = noise[t * 2];   xs[503] = noise[t * 2 + 1];
    }
    __syncthreads();
    int c = tid & 31, kg = tid >> 5;   // 8 k-groups x 32 channels
    float acc = 0.f;
#pragma unroll 7
    for (int f = kg; f < 504; f += 8) acc += xs[f] * w[f * H1_ + c];
    red[kg][c] = acc;
    __syncthreads();
    if (tid < H1_) {
        float a = 0.f;
#pragma unroll
        for (int s = 0; s < 8; ++s) a += red[s][tid];
        y1[t * H1_ + tid] = a;
    }
}

// One block per t: h1row = lrelu(bn(adj[t]@y1 + b)); y2[t][c2] = h1row @ g2w
__global__ __launch_bounds__(256) void k2_adj_fused(const float* __restrict__ adj,
                                                    const float* __restrict__ y1,
                                                    const float* __restrict__ b,
                                                    const float* __restrict__ gamma,
                                                    const float* __restrict__ beta,
                                                    const float* __restrict__ w2,
                                                    float* __restrict__ y2) {
    __shared__ float arow[T_];
    __shared__ float red[8][H1_];
    __shared__ float h1row[H1_];
    int t = blockIdx.x, tid = threadIdx.x;
    for (int u = tid; u < T_; u += 256) arow[u] = adj[t * T_ + u];
    __syncthreads();
    int c = tid & 31, kg = tid >> 5;
    float acc = 0.f;
#pragma unroll 4
    for (int u = kg; u < T_; u += 8) acc += arow[u] * y1[u * H1_ + c];
    red[kg][c] = acc;
    __syncthreads();
    if (tid < H1_) {
        float a = 0.f;
#pragma unroll
        for (int s = 0; s < 8; ++s) a += red[s][tid];
        h1row[tid] = lrelu((a + b[tid]) * gamma[t] + beta[t]);
    }
    __syncthreads();
    if (tid < H2_) {
        float a = 0.f;
#pragma unroll
        for (int cc = 0; cc < H1_; ++cc) a += h1row[cc] * w2[cc * H2_ + tid];
        y2[t * H2_ + tid] = a;
    }
}

// One block per t: xfrow = lrelu(bn(adj[t]@y2 + b2)); part1[t][j] = xfrow @ aw[t*16..t*16+16)
__global__ __launch_bounds__(256) void k3_adj2_aw(const float* __restrict__ adj,
                                                  const float* __restrict__ y2,
                                                  const float* __restrict__ b2,
                                                  const float* __restrict__ gamma,
                                                  const float* __restrict__ beta,
                                                  const float* __restrict__ aw,
                                                  float* __restrict__ part1) {
    __shared__ float arow[T_];
    __shared__ float red[16][H2_];
    __shared__ float xfr[H2_];
    int t = blockIdx.x, tid = threadIdx.x;
    for (int u = tid; u < T_; u += 256) arow[u] = adj[t * T_ + u];
    __syncthreads();
    int c2 = tid & 15, kg = tid >> 4;  // 16 k-groups x 16 channels
    float acc = 0.f;
#pragma unroll 4
    for (int u = kg; u < T_; u += 16) acc += arow[u] * y2[u * H2_ + c2];
    red[kg][c2] = acc;
    __syncthreads();
    if (tid < H2_) {
        float a = 0.f;
#pragma unroll
        for (int s = 0; s < 16; ++s) a += red[s][tid];
        xfr[tid] = lrelu((a + b2[tid]) * gamma[t] + beta[t]);
    }
    __syncthreads();
    float acc0 = 0.f, acc1 = 0.f;
#pragma unroll
    for (int c = 0; c < H2_; ++c) {
        float xv = xfr[c];
        const float* awr = aw + (t * H2_ + c) * T_;
        acc0 += xv * awr[tid];
        if (tid < T_ - 256) acc1 += xv * awr[256 + tid];
    }
    part1[t * T_ + tid] = acc0;
    if (tid < T_ - 256) part1[t * T_ + 256 + tid] = acc1;
}

// Block (r, y=q*2+jb): partial logits over t-quarter q, j-half jb.
// part2[q][r*T+j] = sum_{t in q} dloc[r][t]*av[t][j] + part1[t][j]
__global__ __launch_bounds__(256) void k4_logits_part(const float* __restrict__ dloc,
                                                      const float* __restrict__ av,
                                                      const float* __restrict__ part1,
                                                      float* __restrict__ part2) {
    int r = blockIdx.x;
    int jb = blockIdx.y & 1, q = blockIdx.y >> 1;
    __shared__ float drow[125];
    int tid = threadIdx.x;
    int t0 = q * 125;
    if (tid < 125) drow[tid] = dloc[r * T_ + t0 + tid];
    __syncthreads();
    if (tid >= 250) return;
    int j = jb * 250 + tid;
    float acc = 0.f;
#pragma unroll 5
    for (int i = 0; i < 125; ++i) {
        int t = t0 + i;
        acc += drow[i] * av[t * T_ + j] + part1[t * T_ + j];
    }
    part2[q * (R_ * T_) + r * T_ + j] = acc;
}

// elog[x] = exp(sum_q part2[q][x])
__global__ __launch_bounds__(256) void k4_reduce_exp(const float* __restrict__ part2,
                                                     float* __restrict__ elog) {
    int gid = blockIdx.x * 256 + threadIdx.x;
    if (gid >= R_ * T_) return;
    float v = part2[gid] + part2[R_ * T_ + gid] +
              part2[2 * R_ * T_ + gid] + part2[3 * R_ * T_ + gid];
    elog[gid] = __expf(v);
}

// 4 rows per wave. ALL 16 loads (8 gu + 8 elog) issued first, then an inline-asm
// memory clobber pins them above the compute (scheduler cannot sink loads across
// a volatile asm). Second-half loads use ADDRESS selects (no data dependence on
// the first loads, so no early waitcnt). ~16KB in flight per wave.
__global__ __launch_bounds__(256) void k7_softmax(const float4* __restrict__ gu,
                                                  const float4* __restrict__ elog,
                                                  float4* __restrict__ out) {
    int wave = threadIdx.x >> 6;
    int lane = threadIdx.x & 63;
    int w = blockIdx.x * 4 + wave;   // wave id < 12500
    int row0 = w * 4;
    bool has1 = lane < 61;
    int i0 = lane;
    int i1 = has1 ? 64 + lane : lane;   // address select, not value select

    int rA = row0 % R_;
    int rB = rA + 1 == R_ ? 0 : rA + 1;
    int rC = rB + 1 == R_ ? 0 : rB + 1;
    int rD = rC + 1 == R_ ? 0 : rC + 1;

    const float4* gp = gu + (size_t)row0 * 125;
    const float4* eA = elog + rA * 125;
    const float4* eB = elog + rB * 125;
    const float4* eC = elog + rC * 125;
    const float4* eD = elog + rD * 125;

    // issue all 16 loads back-to-back
    float4 ga0 = gp[i0],       ga1 = gp[i1];
    float4 gb0 = gp[125 + i0], gb1 = gp[125 + i1];
    float4 gc0 = gp[250 + i0], gc1 = gp[250 + i1];
    float4 gd0 = gp[375 + i0], gd1 = gp[375 + i1];
    float4 ea0 = eA[i0], ea1 = eA[i1];
    float4 eb0 = eB[i0], eb1 = eB[i1];
    float4 ec0 = eC[i0], ec1 = eC[i1];
    float4 ed0 = eD[i0], ed1 = eD[i1];

    asm volatile("" ::: "memory");   // scheduling barrier: loads stay above

#define ROWC(G0, G1, E0, E1, RR)                                              \
    do {                                                                      \
        float p0 = E0.x * __builtin_amdgcn_rcpf(-__log2f(G0.x));              \
        float p1 = E0.y * __builtin_amdgcn_rcpf(-__log2f(G0.y));              \
        float p2 = E0.z * __builtin_amdgcn_rcpf(-__log2f(G0.z));              \
        float p3 = E0.w * __builtin_amdgcn_rcpf(-__log2f(G0.w));              \
        float p4 = 0.f, p5 = 0.f, p6 = 0.f, p7 = 0.f;                         \
        if (has1) {                                                           \
            p4 = E1.x * __builtin_amdgcn_rcpf(-__log2f(G1.x));                \
            p5 = E1.y * __builtin_amdgcn_rcpf(-__log2f(G1.y));                \
            p6 = E1.z * __builtin_amdgcn_rcpf(-__log2f(G1.z));                \
            p7 = E1.w * __builtin_amdgcn_rcpf(-__log2f(G1.w));                \
        }                                                                     \
        float s = ((p0 + p1) + (p2 + p3)) + ((p4 + p5) + (p6 + p7));          \
        _Pragma("unroll")                                                     \
        for (int off = 32; off > 0; off >>= 1) s += __shfl_xor(s, off);       \
        float inv = __builtin_amdgcn_rcpf(s);                                 \
        float4* op = out + (size_t)(RR) * 125;                                \
        float4 o0 = {p0 * inv, p1 * inv, p2 * inv, p3 * inv};                 \
        op[i0] = o0;                                                          \
        if (has1) {                                                           \
            float4 o1 = {p4 * inv, p5 * inv, p6 * inv, p7 * inv};             \
            op[64 + lane] = o1;                                               \
        }                                                                     \
    } while (0)

    ROWC(ga0, ga1, ea0, ea1, row0);
    ROWC(gb0, gb1, eb0, eb1, row0 + 1);
    ROWC(gc0, gc1, ec0, ec1, row0 + 2);
    ROWC(gd0, gd1, ed0, ed1, row0 + 3);
#undef ROWC
}

extern "C" void kernel_launch(void* const* d_in, const int* in_sizes, int n_in,
                              void* d_out, int out_size, void* d_ws, size_t ws_size,
                              hipStream_t stream) {
    const float* state  = (const float*)d_in[0];
    const float* dloc   = (const float*)d_in[1];
    const float* noise  = (const float*)d_in[2];
    const float* gu     = (const float*)d_in[3];
    const float* payoff = (const float*)d_in[4];
    const float* adj    = (const float*)d_in[5];
    const float* g1w    = (const float*)d_in[6];
    const float* g1b    = (const float*)d_in[7];
    const float* g2w    = (const float*)d_in[8];
    const float* g2b    = (const float*)d_in[9];
    const float* gamma  = (const float*)d_in[10];
    const float* beta   = (const float*)d_in[11];
    const float* aw     = (const float*)d_in[12];
    const float* av     = (const float*)d_in[13];
    float* out = (float*)d_out;

    float* ws     = (float*)d_ws;
    float* y1     = ws;           // 16000
    float* y2     = ws + 16000;   // 8000
    float* part1  = ws + 24000;   // 500*500 = 250000
    float* part2  = ws + 274000;  // 4*25000 = 100000
    float* elog   = ws + 374000;  // 25000   (total 399000 floats = 1.6 MB)

    k1_xw<<<T_, 256, 0, stream>>>(state, payoff, noise, g1w, y1);
    k2_adj_fused<<<T_, 256, 0, stream>>>(adj, y1, g1b, gamma, beta, g2w, y2);
    k3_adj2_aw<<<T_, 256, 0, stream>>>(adj, y2, g2b, gamma, beta, aw, part1);
    k4_logits_part<<<dim3(R_, 8), 256, 0, stream>>>(dloc, av, part1, part2);
    k4_reduce_exp<<<(R_ * T_ + 255) / 256, 256, 0, stream>>>(part2, elog);
    k7_softmax<<<NROWS_ / 16, 256, 0, stream>>>(
        (const float4*)gu, (const float4*)elog, (float4*)out);
}

// Round 12
// 71.609 us; speedup vs baseline: 1.1013x; 1.0258x over previous
//
#include <hip/hip_runtime.h>

#define T_ 500
#define R_ 50
#define NS_ 1000
#define H1_ 32
#define H2_ 16
#define NEG_ 0.2f
#define NROWS_ (NS_ * R_)   // 50000

__device__ __forceinline__ float lrelu(float x) { return x >= 0.f ? x : NEG_ * x; }

// Full-wave (64 lane) sum via DPP: row_shr 1/2/4/8, row_bcast:15, row_bcast:31.
// Result in lane 63; broadcast with readlane. Pure VALU — no LDS pipe.
__device__ __forceinline__ float wave_sum_dpp(float x) {
    int t;
    t = __builtin_amdgcn_update_dpp(0, __float_as_int(x), 0x111, 0xf, 0xf, true);
    x += __int_as_float(t);
    t = __builtin_amdgcn_update_dpp(0, __float_as_int(x), 0x112, 0xf, 0xf, true);
    x += __int_as_float(t);
    t = __builtin_amdgcn_update_dpp(0, __float_as_int(x), 0x114, 0xf, 0xf, true);
    x += __int_as_float(t);
    t = __builtin_amdgcn_update_dpp(0, __float_as_int(x), 0x118, 0xf, 0xf, true);
    x += __int_as_float(t);
    t = __builtin_amdgcn_update_dpp(0, __float_as_int(x), 0x142, 0xf, 0xf, true);
    x += __int_as_float(t);
    t = __builtin_amdgcn_update_dpp(0, __float_as_int(x), 0x143, 0xf, 0xf, true);
    x += __int_as_float(t);
    return __int_as_float(__builtin_amdgcn_readlane(__float_as_int(x), 63));
}

// One block per t: y1[t][c] = sum_f x[t][f] * gc1_w[f][c],  x=[state(2)|payoff row(500)|noise(2)]
__global__ __launch_bounds__(256) void k1_xw(const float* __restrict__ state,
                                             const float* __restrict__ payoff,
                                             const float* __restrict__ noise,
                                             const float* __restrict__ w,
                                             float* __restrict__ y1) {
    __shared__ float xs[504];
    __shared__ float red[8][H1_];
    int t = blockIdx.x, tid = threadIdx.x;
    for (int u = tid; u < T_; u += 256) xs[2 + u] = payoff[t * T_ + u];
    if (tid == 0) {
        xs[0] = state[t * 2];     xs[1] = state[t * 2 + 1];
        xs[502] = noise[t * 2];   xs[503] = noise[t * 2 + 1];
    }
    __syncthreads();
    int c = tid & 31, kg = tid >> 5;   // 8 k-groups x 32 channels
    float acc = 0.f;
#pragma unroll 7
    for (int f = kg; f < 504; f += 8) acc += xs[f] * w[f * H1_ + c];
    red[kg][c] = acc;
    __syncthreads();
    if (tid < H1_) {
        float a = 0.f;
#pragma unroll
        for (int s = 0; s < 8; ++s) a += red[s][tid];
        y1[t * H1_ + tid] = a;
    }
}

// One block per t: h1row = lrelu(bn(adj[t]@y1 + b)); y2[t][c2] = h1row @ g2w
__global__ __launch_bounds__(256) void k2_adj_fused(const float* __restrict__ adj,
                                                    const float* __restrict__ y1,
                                                    const float* __restrict__ b,
                                                    const float* __restrict__ gamma,
                                                    const float* __restrict__ beta,
                                                    const float* __restrict__ w2,
                                                    float* __restrict__ y2) {
    __shared__ float arow[T_];
    __shared__ float red[8][H1_];
    __shared__ float h1row[H1_];
    int t = blockIdx.x, tid = threadIdx.x;
    for (int u = tid; u < T_; u += 256) arow[u] = adj[t * T_ + u];
    __syncthreads();
    int c = tid & 31, kg = tid >> 5;
    float acc = 0.f;
#pragma unroll 4
    for (int u = kg; u < T_; u += 8) acc += arow[u] * y1[u * H1_ + c];
    red[kg][c] = acc;
    __syncthreads();
    if (tid < H1_) {
        float a = 0.f;
#pragma unroll
        for (int s = 0; s < 8; ++s) a += red[s][tid];
        h1row[tid] = lrelu((a + b[tid]) * gamma[t] + beta[t]);
    }
    __syncthreads();
    if (tid < H2_) {
        float a = 0.f;
#pragma unroll
        for (int cc = 0; cc < H1_; ++cc) a += h1row[cc] * w2[cc * H2_ + tid];
        y2[t * H2_ + tid] = a;
    }
}

// One block per t: xfrow = lrelu(bn(adj[t]@y2 + b2)); part1[t][j] = xfrow @ aw[t*16..t*16+16)
__global__ __launch_bounds__(256) void k3_adj2_aw(const float* __restrict__ adj,
                                                  const float* __restrict__ y2,
                                                  const float* __restrict__ b2,
                                                  const float* __restrict__ gamma,
                                                  const float* __restrict__ beta,
                                                  const float* __restrict__ aw,
                                                  float* __restrict__ part1) {
    __shared__ float arow[T_];
    __shared__ float red[16][H2_];
    __shared__ float xfr[H2_];
    int t = blockIdx.x, tid = threadIdx.x;
    for (int u = tid; u < T_; u += 256) arow[u] = adj[t * T_ + u];
    __syncthreads();
    int c2 = tid & 15, kg = tid >> 4;  // 16 k-groups x 16 channels
    float acc = 0.f;
#pragma unroll 4
    for (int u = kg; u < T_; u += 16) acc += arow[u] * y2[u * H2_ + c2];
    red[kg][c2] = acc;
    __syncthreads();
    if (tid < H2_) {
        float a = 0.f;
#pragma unroll
        for (int s = 0; s < 16; ++s) a += red[s][tid];
        xfr[tid] = lrelu((a + b2[tid]) * gamma[t] + beta[t]);
    }
    __syncthreads();
    float acc0 = 0.f, acc1 = 0.f;
#pragma unroll
    for (int c = 0; c < H2_; ++c) {
        float xv = xfr[c];
        const float* awr = aw + (t * H2_ + c) * T_;
        acc0 += xv * awr[tid];
        if (tid < T_ - 256) acc1 += xv * awr[256 + tid];
    }
    part1[t * T_ + tid] = acc0;
    if (tid < T_ - 256) part1[t * T_ + 256 + tid] = acc1;
}

// Block (r, y=q*2+jb): partial logits over t-quarter q, j-half jb.
// part2[q][r*T+j] = sum_{t in q} dloc[r][t]*av[t][j] + part1[t][j]
__global__ __launch_bounds__(256) void k4_logits_part(const float* __restrict__ dloc,
                                                      const float* __restrict__ av,
                                                      const float* __restrict__ part1,
                                                      float* __restrict__ part2) {
    int r = blockIdx.x;
    int jb = blockIdx.y & 1, q = blockIdx.y >> 1;
    __shared__ float drow[125];
    int tid = threadIdx.x;
    int t0 = q * 125;
    if (tid < 125) drow[tid] = dloc[r * T_ + t0 + tid];
    __syncthreads();
    if (tid >= 250) return;
    int j = jb * 250 + tid;
    float acc = 0.f;
#pragma unroll 5
    for (int i = 0; i < 125; ++i) {
        int t = t0 + i;
        acc += drow[i] * av[t * T_ + j] + part1[t * T_ + j];
    }
    part2[q * (R_ * T_) + r * T_ + j] = acc;
}

// elog[x] = exp(sum_q part2[q][x])
__global__ __launch_bounds__(256) void k4_reduce_exp(const float* __restrict__ part2,
                                                     float* __restrict__ elog) {
    int gid = blockIdx.x * 256 + threadIdx.x;
    if (gid >= R_ * T_) return;
    float v = part2[gid] + part2[R_ * T_ + gid] +
              part2[2 * R_ * T_ + gid] + part2[3 * R_ * T_ + gid];
    elog[gid] = __expf(v);
}

// One wave per row, DPP wave-sum (no LDS-pipe cross-lane chain).
// softmax identity: softmax(logit - log(-log u)) = elog * rcp(-log2 u) / rowsum.
__global__ __launch_bounds__(256) void k7_softmax(const float4* __restrict__ gu,
                                                  const float4* __restrict__ elog,
                                                  float4* __restrict__ out) {
    int wave = threadIdx.x >> 6;
    int lane = threadIdx.x & 63;
    int row = blockIdx.x * 4 + wave;  // < 50000
    int r = row % R_;
    const float4* grow = gu + (size_t)row * 125;
    const float4* erow = elog + r * 125;
    bool has1 = lane < 61;

    float4 g0 = grow[lane];
    float4 e0 = erow[lane];
    float4 g1, e1;
    if (has1) {
        g1 = grow[64 + lane];
        e1 = erow[64 + lane];
    }
    float p[8];
    p[0] = e0.x * __builtin_amdgcn_rcpf(-__log2f(g0.x));
    p[1] = e0.y * __builtin_amdgcn_rcpf(-__log2f(g0.y));
    p[2] = e0.z * __builtin_amdgcn_rcpf(-__log2f(g0.z));
    p[3] = e0.w * __builtin_amdgcn_rcpf(-__log2f(g0.w));
    if (has1) {
        p[4] = e1.x * __builtin_amdgcn_rcpf(-__log2f(g1.x));
        p[5] = e1.y * __builtin_amdgcn_rcpf(-__log2f(g1.y));
        p[6] = e1.z * __builtin_amdgcn_rcpf(-__log2f(g1.z));
        p[7] = e1.w * __builtin_amdgcn_rcpf(-__log2f(g1.w));
    } else {
        p[4] = p[5] = p[6] = p[7] = 0.f;
    }
    float s = ((p[0] + p[1]) + (p[2] + p[3])) + ((p[4] + p[5]) + (p[6] + p[7]));
    float tot = wave_sum_dpp(s);
    float inv = __builtin_amdgcn_rcpf(tot);

    float4* orow = out + (size_t)row * 125;
    float4 o0 = {p[0] * inv, p[1] * inv, p[2] * inv, p[3] * inv};
    orow[lane] = o0;
    if (has1) {
        float4 o1 = {p[4] * inv, p[5] * inv, p[6] * inv, p[7] * inv};
        orow[64 + lane] = o1;
    }
}

extern "C" void kernel_launch(void* const* d_in, const int* in_sizes, int n_in,
                              void* d_out, int out_size, void* d_ws, size_t ws_size,
                              hipStream_t stream) {
    const float* state  = (const float*)d_in[0];
    const float* dloc   = (const float*)d_in[1];
    const float* noise  = (const float*)d_in[2];
    const float* gu     = (const float*)d_in[3];
    const float* payoff = (const float*)d_in[4];
    const float* adj    = (const float*)d_in[5];
    const float* g1w    = (const float*)d_in[6];
    const float* g1b    = (const float*)d_in[7];
    const float* g2w    = (const float*)d_in[8];
    const float* g2b    = (const float*)d_in[9];
    const float* gamma  = (const float*)d_in[10];
    const float* beta   = (const float*)d_in[11];
    const float* aw     = (const float*)d_in[12];
    const float* av     = (const float*)d_in[13];
    float* out = (float*)d_out;

    float* ws     = (float*)d_ws;
    float* y1     = ws;           // 16000
    float* y2     = ws + 16000;   // 8000
    float* part1  = ws + 24000;   // 500*500 = 250000
    float* part2  = ws + 274000;  // 4*25000 = 100000
    float* elog   = ws + 374000;  // 25000   (total 399000 floats = 1.6 MB)

    k1_xw<<<T_, 256, 0, stream>>>(state, payoff, noise, g1w, y1);
    k2_adj_fused<<<T_, 256, 0, stream>>>(adj, y1, g1b, gamma, beta, g2w, y2);
    k3_adj2_aw<<<T_, 256, 0, stream>>>(adj, y2, g2b, gamma, beta, aw, part1);
    k4_logits_part<<<dim3(R_, 8), 256, 0, stream>>>(dloc, av, part1, part2);
    k4_reduce_exp<<<(R_ * T_ + 255) / 256, 256, 0, stream>>>(part2, elog);
    k7_softmax<<<NROWS_ / 4, 256, 0, stream>>>(
        (const float4*)gu, (const float4*)elog, (float4*)out);
}